// Round 1
// baseline (96.440 us; speedup 1.0000x reference)
//
#include <hip/hip_runtime.h>

// Embedder: counts = scatter_add over tokens -> (B, DEPTH) float32
// B=1024, S=200, DEPTH=100000. Output is 409.6 MB -> write-BW bound.
//
// One block per batch row:
//   phase 1: zero the 100000-float row with float4 stores (coalesced)
//   phase 2: __syncthreads, then 200 lanes atomicAdd into the same row.
// Each block only touches its own row, so no inter-block ordering needed.

#define EMB_DEPTH 100000
#define EMB_SEQ   200

__global__ __launch_bounds__(256) void embedder_count_kernel(
    const int*   __restrict__ tokens,     // (B, S) int32
    const float* __restrict__ on_values,  // (B, S) float32
    float*       __restrict__ out)        // (B, DEPTH) float32
{
    const int b   = blockIdx.x;
    const int tid = threadIdx.x;

    // Row base: b * 100000 floats = b * 400000 bytes, 16B-aligned.
    float* row = out + (size_t)b * EMB_DEPTH;
    float4* row4 = reinterpret_cast<float4*>(row);
    const float4 z = make_float4(0.0f, 0.0f, 0.0f, 0.0f);

    // 100000 / 4 = 25000 float4 stores per row, ~98 per thread.
    #pragma unroll 4
    for (int i = tid; i < EMB_DEPTH / 4; i += 256) {
        row4[i] = z;
    }

    __syncthreads();  // make this block's zero-stores visible before atomics

    if (tid < EMB_SEQ) {
        const int   t = tokens[(size_t)b * EMB_SEQ + tid];
        const float v = on_values[(size_t)b * EMB_SEQ + tid];
        atomicAdd(row + t, v);
    }
}

extern "C" void kernel_launch(void* const* d_in, const int* in_sizes, int n_in,
                              void* d_out, int out_size, void* d_ws, size_t ws_size,
                              hipStream_t stream) {
    const int*   tokens    = (const int*)  d_in[0];
    const float* on_values = (const float*)d_in[1];
    float*       out       = (float*)      d_out;

    const int B = 1024;  // out_size == B * EMB_DEPTH
    embedder_count_kernel<<<B, 256, 0, stream>>>(tokens, on_values, out);
}

// Round 2
// 78.091 us; speedup vs baseline: 1.2350x; 1.2350x over previous
//
#include <hip/hip_runtime.h>

// Embedder: counts = scatter_add(one_hot(tokens)) -> (B, DEPTH) float32
// B=1024, S=200, DEPTH=100000. Output = 409.6 MB -> pure write-BW bound.
//
// Single-pass, no global atomics: each block owns a 1/8-row segment
// (12500 floats = 50 KB LDS -> 3 blocks/CU). Build counts in LDS with
// ds_add_f32, then stream the merged segment to global exactly once
// with float4 stores. Every output cacheline is written exactly once;
// no global read-modify-write; LDS phases of one block overlap with the
// write phases of the other two resident blocks on the CU.

#define EMB_DEPTH 100000
#define EMB_SEQ   200
#define NSEG      8
#define SEGSZ     (EMB_DEPTH / NSEG)   // 12500 floats = 50 KB

__global__ __launch_bounds__(256) void embedder_seg_kernel(
    const int*   __restrict__ tokens,     // (B, S) int32
    const float* __restrict__ on_values,  // (B, S) float32
    float*       __restrict__ out)        // (B, DEPTH) float32
{
    __shared__ float cnt[SEGSZ];          // 50,000 B static LDS

    const int tid = threadIdx.x;
    const int b   = blockIdx.x >> 3;      // row
    const int seg = blockIdx.x & (NSEG - 1);
    const int lo  = seg * SEGSZ;          // segment's first token id

    // Phase 1: zero the LDS segment (~49 ds_write_b32 per thread).
    for (int i = tid; i < SEGSZ; i += 256) cnt[i] = 0.0f;
    __syncthreads();

    // Phase 2: scatter this row's tokens that land in our segment.
    if (tid < EMB_SEQ) {
        const int t = tokens[(size_t)b * EMB_SEQ + tid];
        const unsigned r = (unsigned)(t - lo);
        if (r < (unsigned)SEGSZ) {
            atomicAdd(&cnt[r], on_values[(size_t)b * EMB_SEQ + tid]);  // ds_add_f32
        }
    }
    __syncthreads();

    // Phase 3: merged write-out, float4, each line touched exactly once.
    // Base byte offset = b*400000 + seg*50000 -> 16B aligned.
    float4* out4 = reinterpret_cast<float4*>(out + (size_t)b * EMB_DEPTH + lo);
    const float4* c4 = reinterpret_cast<const float4*>(cnt);
    #pragma unroll 4
    for (int i = tid; i < SEGSZ / 4; i += 256) {   // 3125 float4 per block
        out4[i] = c4[i];
    }
}

extern "C" void kernel_launch(void* const* d_in, const int* in_sizes, int n_in,
                              void* d_out, int out_size, void* d_ws, size_t ws_size,
                              hipStream_t stream) {
    const int*   tokens    = (const int*)  d_in[0];
    const float* on_values = (const float*)d_in[1];
    float*       out       = (float*)      d_out;

    const int B = in_sizes[0] / EMB_SEQ;   // 1024
    embedder_seg_kernel<<<B * NSEG, 256, 0, stream>>>(tokens, on_values, out);
}